// Round 1
// baseline (38.591 us; speedup 1.0000x reference)
//
#include <hip/hip_runtime.h>
#include <hip/hip_bf16.h>

#define EPS 1e-5f

// Prep: gw[i] = gamma[i] * W[0][i];  consts[0] = sum(gw); consts[1] = sum(beta*W) + bias
__global__ __launch_bounds__(256) void prep_kernel(
    const float* __restrict__ g, const float* __restrict__ beta,
    const float* __restrict__ W, const float* __restrict__ bias,
    float* __restrict__ gw, float* __restrict__ consts) {
    int t = threadIdx.x;
    float sgw = 0.f, sbw = 0.f;
    for (int i = t; i < 768; i += 256) {
        float gv = g[i] * W[i];
        gw[i] = gv;
        sgw += gv;
        sbw += beta[i] * W[i];
    }
    // wave reduce (64 lanes)
    for (int m = 32; m; m >>= 1) {
        sgw += __shfl_xor(sgw, m);
        sbw += __shfl_xor(sbw, m);
    }
    __shared__ float red[8];
    int wid = t >> 6;
    if ((t & 63) == 0) { red[wid * 2] = sgw; red[wid * 2 + 1] = sbw; }
    __syncthreads();
    if (t == 0) {
        float a = red[0] + red[2] + red[4] + red[6];
        float b = red[1] + red[3] + red[5] + red[7];
        consts[0] = a;
        consts[1] = b + bias[0];
    }
}

// One wave (64 lanes) per output row. Row = (b, n) of the sliced tensor
// x[:, 1:, :]; source row pointer = x + (b*257 + n + 1)*768.
// Single pass: s1 = sum(x), s2 = sum(x^2), s3 = sum(x * gw).
__global__ __launch_bounds__(256) void head_kernel(
    const float* __restrict__ x, const float* __restrict__ gw,
    const float* __restrict__ consts, float* __restrict__ out) {
    const int lane = threadIdx.x & 63;
    const int wid  = threadIdx.x >> 6;
    const int row  = blockIdx.x * 4 + wid;          // 0 .. 65535
    const int b    = row >> 8;                       // / 256
    const int n    = row & 255;
    const float* __restrict__ xr = x + (size_t)(b * 257 + n + 1) * 768;

    float s1 = 0.f, s2 = 0.f, s3 = 0.f;
#pragma unroll
    for (int k = 0; k < 3; ++k) {
        int idx = (lane + k * 64) * 4;               // float4 granularity
        float4 v = *reinterpret_cast<const float4*>(xr + idx);
        float4 w = *reinterpret_cast<const float4*>(gw + idx);
        s1 += v.x + v.y + v.z + v.w;
        s2 += v.x * v.x + v.y * v.y + v.z * v.z + v.w * v.w;
        s3 += v.x * w.x + v.y * w.y + v.z * w.z + v.w * w.w;
    }
    // 64-lane butterfly reduce
    for (int m = 32; m; m >>= 1) {
        s1 += __shfl_xor(s1, m);
        s2 += __shfl_xor(s2, m);
        s3 += __shfl_xor(s3, m);
    }
    if (lane == 0) {
        const float inv_e = 1.0f / 768.0f;
        float mu  = s1 * inv_e;
        float var = s2 * inv_e - mu * mu;
        float rs  = rsqrtf(var + EPS);
        float logit = rs * (s3 - mu * consts[0]) + consts[1];
        out[row] = 1.0f / (1.0f + __expf(-logit));
    }
}

extern "C" void kernel_launch(void* const* d_in, const int* in_sizes, int n_in,
                              void* d_out, int out_size, void* d_ws, size_t ws_size,
                              hipStream_t stream) {
    const float* x     = (const float*)d_in[0];   // (256, 257, 768)
    const float* gamma = (const float*)d_in[1];   // (768,)
    const float* beta  = (const float*)d_in[2];   // (768,)
    const float* W     = (const float*)d_in[3];   // (1, 768)
    const float* bias  = (const float*)d_in[4];   // (1,)
    float* out = (float*)d_out;                   // (256, 256, 1) = 65536 floats

    float* gw     = (float*)d_ws;                 // 768 floats
    float* consts = gw + 768;                     // 2 floats

    prep_kernel<<<1, 256, 0, stream>>>(gamma, beta, W, bias, gw, consts);

    const int rows = 256 * 256;                   // 65536 rows, 1 wave each
    head_kernel<<<rows / 4, 256, 0, stream>>>(x, gw, consts, out);
}

// Round 2
// 35.163 us; speedup vs baseline: 1.0975x; 1.0975x over previous
//
#include <hip/hip_runtime.h>
#include <hip/hip_bf16.h>

#define EPS 1e-5f

// Fully fused: slice + LayerNorm + dot(W) + bias + sigmoid, single pass.
// logit = rs*(sum(x*gw) - mu*sum(gw)) + sum(beta*W) + bias,  gw = gamma*W
// Per block: prologue computes gw[768] + 2 consts into LDS (replaces the
// former prep kernel -> no inter-kernel dependency in the graph).
// Main: 4 waves/block, each wave processes 4 rows with 16 lanes/row, so one
// butterfly step reduces 4 rows at once (12 shfl per wave vs 18 per row before).
__global__ __launch_bounds__(256) void head_kernel(
    const float* __restrict__ x, const float* __restrict__ gamma,
    const float* __restrict__ beta, const float* __restrict__ W,
    const float* __restrict__ bias, float* __restrict__ out) {
    __shared__ float s_gw[768];
    __shared__ float s_red[8];
    __shared__ float s_c[2];

    const int t = threadIdx.x;

    // ---- per-block prologue: gw into LDS + consts (gamma/beta/W are L1/L2-hot) ----
    {
        float sgw = 0.f, sbw = 0.f;
#pragma unroll
        for (int i = t; i < 768; i += 256) {
            float w  = W[i];
            float gv = gamma[i] * w;
            s_gw[i] = gv;
            sgw += gv;
            sbw += beta[i] * w;
        }
#pragma unroll
        for (int m = 32; m; m >>= 1) {
            sgw += __shfl_xor(sgw, m);
            sbw += __shfl_xor(sbw, m);
        }
        const int wv = t >> 6;
        if ((t & 63) == 0) { s_red[wv * 2] = sgw; s_red[wv * 2 + 1] = sbw; }
        __syncthreads();
        if (t == 0) {
            s_c[0] = s_red[0] + s_red[2] + s_red[4] + s_red[6];
            s_c[1] = s_red[1] + s_red[3] + s_red[5] + s_red[7] + bias[0];
        }
        __syncthreads();
    }

    // ---- main: 16 rows/block = 4 waves x 4 rows; 16 lanes per row ----
    const int lane = t & 63;
    const int wv   = t >> 6;
    const int sl   = lane & 15;   // sub-lane within the row's 16-lane group
    const int grp  = lane >> 4;   // which of the wave's 4 rows
    const int row  = blockIdx.x * 16 + wv * 4 + grp;   // 0 .. 65535
    const int b    = row >> 8;
    const int n    = row & 255;
    const float* __restrict__ xr = x + (size_t)(b * 257 + n + 1) * 768;

    float s1 = 0.f, s2 = 0.f, s3 = 0.f;
#pragma unroll
    for (int k = 0; k < 12; ++k) {
        const int idx = sl * 4 + k * 64;   // 16 lanes x float4 = contiguous 256B/group
        float4 v = *reinterpret_cast<const float4*>(xr + idx);
        float4 w = *reinterpret_cast<const float4*>(s_gw + idx);
        s1 += v.x + v.y + v.z + v.w;
        s2 += v.x * v.x + v.y * v.y + v.z * v.z + v.w * v.w;
        s3 += v.x * w.x + v.y * w.y + v.z * w.z + v.w * w.w;
    }
    // butterfly over the 16-lane group: reduces all 4 rows of the wave at once
#pragma unroll
    for (int m = 8; m; m >>= 1) {
        s1 += __shfl_xor(s1, m);
        s2 += __shfl_xor(s2, m);
        s3 += __shfl_xor(s3, m);
    }
    if (sl == 0) {
        const float inv_e = 1.0f / 768.0f;
        float mu  = s1 * inv_e;
        float var = s2 * inv_e - mu * mu;
        float rs  = rsqrtf(var + EPS);
        float logit = rs * (s3 - mu * s_c[0]) + s_c[1];
        out[row] = 1.0f / (1.0f + __expf(-logit));   // lanes 0/16/32/48 -> 16B store
    }
}

extern "C" void kernel_launch(void* const* d_in, const int* in_sizes, int n_in,
                              void* d_out, int out_size, void* d_ws, size_t ws_size,
                              hipStream_t stream) {
    const float* x     = (const float*)d_in[0];   // (256, 257, 768)
    const float* gamma = (const float*)d_in[1];   // (768,)
    const float* beta  = (const float*)d_in[2];   // (768,)
    const float* W     = (const float*)d_in[3];   // (1, 768)
    const float* bias  = (const float*)d_in[4];   // (1,)
    float* out = (float*)d_out;                   // 65536 floats

    const int rows = 256 * 256;                   // 16 rows per block
    head_kernel<<<rows / 16, 256, 0, stream>>>(x, gamma, beta, W, bias, out);
}